// Round 10
// baseline (144.663 us; speedup 1.0000x reference)
//
#include <hip/hip_runtime.h>
#include <math.h>

#define N_TOK 40
#define N1    41      // N_TOK + 1
#define BS    8
#define DD    256     // D
#define HH    256     // H
#define NTRI  10660   // C(41,3)
#define NPAIR 780     // pairs (i,k) with k-i>=2
#define ROWF  (BS * N1 * HH)  // 83968 floats per [b][t][h] array
#define MNEG  (-1e38f)
#define DPB   256     // DP thread-mapping constant (bit-exact vs prior rounds)
#define GPB   13      // blocks per batch group
#define NBF   (BS * GPB)   // 104 blocks
#define THR   1024    // threads per block (16 waves)
#define SCB   12      // score blocks per group; block 12 = DP block
#define QMAX  65      // pairs per score block: 65 * 12 = 780

// ---- persistent sync state (module .bss: zero at load) ----
// Per-group lines 4 KB apart: [b][0] = proj arrivals (13), [b][64] = score
// arrivals (12). The group's DP block is the last user of its two counters
// and resets them before exit; kernel-end flush + stream ordering make the
// resets visible to the next launch / graph replay.
__device__ unsigned long long g_sync[BS][512];

// ---------------- DP helpers (verbatim) ----------------
__device__ __forceinline__ int tri_base(int i) { return (i * (81 - i)) >> 1; }
#define BIDX(i, j) (tri_base(i) + ((j) - (i) - 1))

constexpr int soff(int W) {
    int s = 0;
    for (int v = 2; v < W; ++v) s += (N1 - v) * (v - 1);
    return s;
}
constexpr int pick_T(int m, int nj) {
    int T = 1;
    while (T < 16 && m * (T * 2) <= DPB && T < nj) T *= 2;
    return T;
}

template<int W>
__device__ __forceinline__ void dp_step(float* __restrict__ Btri,
                                        const float* __restrict__ Sl, int tid)
{
    constexpr int m    = N1 - W;
    constexpr int nj   = W - 1;
    constexpr int T    = pick_T(m, nj);
    constexpr int CH   = (nj + T - 1) / T;
    constexpr int base = soff(W);

    if (tid < m * T) {
        const int i = tid / T;
        const int h = tid % T;
        const int k = i + W;

        float g[CH];
        #pragma unroll
        for (int q = 0; q < CH; ++q) {
            int jp = h + q * T;
            bool live = (q < CH - 1) || (jp < nj);
            int jj = live ? jp : 0;
            float v = Sl[base + i * nj + jj]
                    + Btri[BIDX(i, i + 1 + jj)]
                    + Btri[BIDX(i + 1 + jj, k)];
            g[q] = live ? v : MNEG;
        }
        float mx = g[0];
        #pragma unroll
        for (int q = 1; q < CH; ++q) mx = fmaxf(mx, g[q]);
        float s = 0.f;
        #pragma unroll
        for (int q = 0; q < CH; ++q) s += __expf(g[q] - mx);
        #pragma unroll
        for (int d = 1; d < T; d <<= 1) {
            float mo = __shfl_xor(mx, d);
            float so = __shfl_xor(s, d);
            float nm = fmaxf(mx, mo);
            s = s * __expf(mx - nm) + so * __expf(mo - nm);
            mx = nm;
        }
        if (h == 0)
            Btri[BIDX(i, k)] = mx + __logf(s);
    }
    __syncthreads();
}

template<int W>
__device__ __forceinline__ void dp_from(float* __restrict__ Btri,
                                        const float* __restrict__ Sl, int tid)
{
    dp_step<W>(Btri, Sl, tid);
    if constexpr (W + 1 <= N_TOK) dp_from<W + 1>(Btri, Sl, tid);
}

// ------- Fused, 104 x 1024: proj(flat TLP partition) -> [per-b flag] ->
// score(mod-12 interleave, blocks 0..11) -> [per-b ctr] -> dp (block 12)
__global__ __launch_bounds__(THR) void k_fused(
    const float* __restrict__ enc, const float* __restrict__ W1,
    const float* __restrict__ b1v, const float* __restrict__ W2,
    const float* __restrict__ b2,  const int* __restrict__ lengths,
    float* __restrict__ P, float* __restrict__ Qb, float* __restrict__ Dd,
    float* __restrict__ S, float* __restrict__ out)
{
    const int tid = threadIdx.x;
    const int blk = blockIdx.x;
    const int b   = blk / GPB;        // batch group
    const int g   = blk - b * GPB;    // block index within group (0..12)

    __shared__ __align__(16) struct { float Sl[NTRI]; float Btri[820]; } sh;

    // ======== phase 1: proj, flat (t,h) partition over the group's threads.
    // idx = g*1024+tid < 10496: t = idx>>8, h = idx&255. Per d: 2 coalesced
    // W1 column loads + 1 wave-uniform enc load + 2 fmafs. 10496 live threads
    // per group (~4 waves/SIMD on its CUs) -> load latency hidden by TLP
    // (R7 measured the 1-wave version at ~375 cyc/d-iter, Occupancy 1.9%).
    // Per-(b,t,h) ascending-d fmaf chain + epilogue verbatim -> bits equal.
    {
        const int idx = g * 1024 + tid;
        if (idx < N1 * HH) {
            const int t = idx >> 8;
            const int h = idx & 255;
            const float* erow = enc + (t * BS + b) * DD;
            const float* Wp = W1 + h;            // W1[d*HH + h]
            const float* Wq = W1 + DD * HH + h;  // W1[(DD+d)*HH + h]
            float a = 0.f, c = 0.f;
            #pragma unroll 8
            for (int d = 0; d < DD; ++d) {
                float ev = erow[d];              // wave-uniform
                float wp = Wp[d * HH];           // coalesced across h
                float wq = Wq[d * HH];
                a = fmaf(ev, wp, a);
                c = fmaf(ev, wq, c);
            }
            const int base = ((b * N1) + t) * HH + h;
            P[base]  = a;
            Qb[base] = c + b1v[h];
            Dd[base] = a - c;
        }
        __syncthreads();
        if (tid == 0) {
            __threadfence();
            __hip_atomic_fetch_add(&g_sync[b][0], 1ull, __ATOMIC_RELEASE,
                                   __HIP_MEMORY_SCOPE_AGENT);
        }
    }

    // ---- barrier 1 (per-group): wait for this group's 13 proj arrivals.
    if (tid == 0) {
        while (__hip_atomic_load(&g_sync[b][0], __ATOMIC_RELAXED,
                                 __HIP_MEMORY_SCOPE_AGENT) < (unsigned long long)GPB)
            __builtin_amdgcn_s_sleep(16);
        __threadfence();   // acquire before reading P/Qb/Dd
    }
    __syncthreads();

    if (g < SCB) {
        // ======== phase 2: score — block g takes pairs p = q*12+g, q=0..64
        // (mod-12 interleave of the w-descending list). Verbatim R6.
        const int grp = tid >> 4;
        const int t   = tid & 15;

        for (int q = grp; q < QMAX; q += 64) {
            const int p = q * 12 + g;
            int c = (int)((sqrtf(8.f * (float)p + 1.f) - 1.f) * 0.5f);
            while ((c + 1) * (c + 2) / 2 <= p) ++c;
            while (c * (c + 1) / 2 > p) --c;
            const int w    = 40 - c;
            const int i    = p - c * (c + 1) / 2;
            const int k    = i + w;
            const int nj   = w - 1;
            const int n2   = w - 2;
            const int base = n2 * (n2 + 1) * (119 - 2 * n2) / 6;   // == soff(w)

            const float4* Pr  = (const float4*)(P  + ((b * N1 + i) << 8)) + t * 4;
            const float4* Qr  = (const float4*)(Qb + ((b * N1 + k) << 8)) + t * 4;
            const float4* W2r = (const float4*)(W2) + t * 8;

            float4 pp[4], qq[4], wa[4], wb[4];
            #pragma unroll
            for (int qi = 0; qi < 4; ++qi) {
                pp[qi] = Pr[qi]; qq[qi] = Qr[qi];
                wa[qi] = W2r[qi * 2]; wb[qi] = W2r[qi * 2 + 1];
            }
            const float bb0 = b2[0], bb1 = b2[1];

            const float4* Drow = (const float4*)(Dd + ((b * N1 + i + 1) << 8)) + t * 4;
            float* Sout = S + b * NTRI + base + i * nj;

            for (int jp = 0; jp < nj; ++jp) {
                float s0 = 0.f, s1 = 0.f;
                #pragma unroll
                for (int qi = 0; qi < 4; ++qi) {
                    float4 dd = Drow[qi];
                    float r0 = fmaxf(dd.x + qq[qi].x - pp[qi].x, 0.f);
                    float r1 = fmaxf(dd.y + qq[qi].y - pp[qi].y, 0.f);
                    float r2 = fmaxf(dd.z + qq[qi].z - pp[qi].z, 0.f);
                    float r3 = fmaxf(dd.w + qq[qi].w - pp[qi].w, 0.f);
                    s0 = fmaf(r0, wa[qi].x, s0); s1 = fmaf(r0, wa[qi].y, s1);
                    s0 = fmaf(r1, wa[qi].z, s0); s1 = fmaf(r1, wa[qi].w, s1);
                    s0 = fmaf(r2, wb[qi].x, s0); s1 = fmaf(r2, wb[qi].y, s1);
                    s0 = fmaf(r3, wb[qi].z, s0); s1 = fmaf(r3, wb[qi].w, s1);
                }
                #pragma unroll
                for (int d = 1; d < 16; d <<= 1) {
                    s0 += __shfl_xor(s0, d);
                    s1 += __shfl_xor(s1, d);
                }
                if (t == 0) {
                    float S0 = s0 + bb0, S1 = s1 + bb1;
                    Sout[jp] = fmaxf(S0, S1) + log1pf(__expf(-fabsf(S0 - S1)));
                }
                Drow += 64;
            }
        }

        // ---- arrive score counter (12 per line, 8 lines) and exit
        __syncthreads();
        if (tid == 0) {
            __threadfence();
            __hip_atomic_fetch_add(&g_sync[b][64], 1ull, __ATOMIC_RELEASE,
                                   __HIP_MEMORY_SCOPE_AGENT);
        }
        return;
    }

    // ======== block 12: wait for this batch's 12 score arrivals
    if (tid == 0) {
        while (__hip_atomic_load(&g_sync[b][64], __ATOMIC_RELAXED,
                                 __HIP_MEMORY_SCOPE_AGENT) < (unsigned long long)SCB)
            __builtin_amdgcn_s_sleep(16);
        __threadfence();
    }
    __syncthreads();

    // ======== phase 3: DP for batch b (verbatim; threads >=256 excluded by
    // tid < m*T inside dp_step, all 16 waves join the barriers)
    {
        const float4* src = (const float4*)(S + b * NTRI);
        float4* dst = (float4*)sh.Sl;
        for (int x = tid; x < NTRI / 4; x += THR) dst[x] = src[x];
        if (tid < N_TOK) sh.Btri[tri_base(tid)] = 0.f;
        __syncthreads();

        dp_from<2>(sh.Btri, sh.Sl, tid);

        if (tid == 0) {
            int L = lengths[b];
            out[b] = sh.Btri[BIDX(0, L)];
        }
    }

    // ---- reset this group's counters (we are their last user this launch)
    if (tid == 0) {
        __hip_atomic_store(&g_sync[b][0], 0ull, __ATOMIC_RELAXED,
                           __HIP_MEMORY_SCOPE_AGENT);
        __hip_atomic_store(&g_sync[b][64], 0ull, __ATOMIC_RELAXED,
                           __HIP_MEMORY_SCOPE_AGENT);
    }
}

extern "C" void kernel_launch(void* const* d_in, const int* in_sizes, int n_in,
                              void* d_out, int out_size, void* d_ws, size_t ws_size,
                              hipStream_t stream)
{
    const float* enc = (const float*)d_in[0];
    const float* W1  = (const float*)d_in[1];
    const float* b1  = (const float*)d_in[2];
    const float* W2  = (const float*)d_in[3];
    const float* b2  = (const float*)d_in[4];
    const int* lengths = (const int*)d_in[5];

    float* ws = (float*)d_ws;
    float* P  = ws;
    float* Qb = ws + ROWF;
    float* Dd = ws + 2 * ROWF;
    float* S  = ws + 3 * ROWF;

    k_fused<<<dim3(NBF), dim3(THR), 0, stream>>>(
        enc, W1, b1, W2, b2, lengths, P, Qb, Dd, S, (float*)d_out);
}